// Round 1
// baseline (792.444 us; speedup 1.0000x reference)
//
#include <hip/hip_runtime.h>

// Problem constants (fixed by the reference file)
#define NN 50000     // nodes
#define NE 800000    // edges
#define HD 64        // feature dim (in and hidden)
#define NG 512       // graphs

// ---------------------------------------------------------------------------
// zero a contiguous int region (deg | pooled | cnt are laid out contiguously)
__global__ void zero_kernel(int* __restrict__ p, int n) {
    int i = blockIdx.x * blockDim.x + threadIdx.x;
    if (i < n) p[i] = 0;
}

// degree over aggregation targets (col); self-loop added later as +1
__global__ void deg_kernel(const int* __restrict__ col, int* __restrict__ deg) {
    int e = blockIdx.x * blockDim.x + threadIdx.x;
    if (e < NE) atomicAdd(&deg[col[e]], 1);
}

__global__ void dinv_kernel(const int* __restrict__ deg, float* __restrict__ dinv) {
    int i = blockIdx.x * blockDim.x + threadIdx.x;
    if (i < NN) dinv[i] = rsqrtf((float)(deg[i] + 1));  // +1 self-loop; deg>=1 always
}

// ---------------------------------------------------------------------------
// h = maybe_relu(in) @ W    in: [NN,64], W: [64,64].  NN = 3125 * 16 exactly.
// 256 threads/block, 16 rows/block, 4 outputs/thread.
__global__ __launch_bounds__(256) void gemm64(const float* __restrict__ in,
                                              const float* __restrict__ W,
                                              float* __restrict__ out, int relu) {
    __shared__ float Ws[64][64];   // 16 KB
    __shared__ float Is[16][64];   // 4 KB
    int t = threadIdx.x;
    for (int i = t; i < 64 * 64; i += 256) Ws[i >> 6][i & 63] = W[i];
    int row0 = blockIdx.x * 16;
    for (int i = t; i < 16 * 64; i += 256) {
        float v = in[(row0 + (i >> 6)) * HD + (i & 63)];
        Is[i >> 6][i & 63] = relu ? fmaxf(v, 0.f) : v;
    }
    __syncthreads();
    int c = t & 63, r4 = t >> 6;  // r4 in 0..3
    float a0 = 0.f, a1 = 0.f, a2 = 0.f, a3 = 0.f;
#pragma unroll
    for (int k = 0; k < 64; ++k) {
        float w = Ws[k][c];
        a0 += Is[r4 + 0][k] * w;
        a1 += Is[r4 + 4][k] * w;
        a2 += Is[r4 + 8][k] * w;
        a3 += Is[r4 + 12][k] * w;
    }
    out[(row0 + r4 + 0) * HD + c] = a0;
    out[(row0 + r4 + 4) * HD + c] = a1;
    out[(row0 + r4 + 8) * HD + c] = a2;
    out[(row0 + r4 + 12) * HD + c] = a3;
}

// out[i,d] = dinv[i]^2 * h[i,d] + b[d]   (self-loop message + bias)
__global__ void init_out(float* __restrict__ out, const float* __restrict__ h,
                         const float* __restrict__ dinv, const float* __restrict__ b) {
    int tid = blockIdx.x * blockDim.x + threadIdx.x;  // NN*64 threads
    int i = tid >> 6, d = tid & 63;
    if (i < NN) {
        float di = dinv[i];
        out[tid] = di * di * h[tid] + b[d];
    }
}

// out[col,d] += dinv[row]*dinv[col] * h[row,d]  — one lane per (edge, channel)
__global__ void edge_scatter(float* __restrict__ out, const float* __restrict__ h,
                             const int* __restrict__ row, const int* __restrict__ col,
                             const float* __restrict__ dinv) {
    int tid = blockIdx.x * blockDim.x + threadIdx.x;  // NE*64 threads
    int e = tid >> 6, d = tid & 63;
    if (e < NE) {
        int r = row[e], c = col[e];
        float nrm = dinv[r] * dinv[c];
        atomicAdd(&out[c * HD + d], nrm * h[r * HD + d]);
    }
}

// pooled[batch[i],d] += in[i,d]; cnt[batch[i]] += 1 (lane 0)
__global__ void pool_kernel(const float* __restrict__ in, const int* __restrict__ batch,
                            float* __restrict__ pooled, float* __restrict__ cnt) {
    int tid = blockIdx.x * blockDim.x + threadIdx.x;  // NN*64 threads
    int i = tid >> 6, d = tid & 63;
    if (i < NN) {
        int g = batch[i];
        atomicAdd(&pooled[g * HD + d], in[tid]);
        if (d == 0) atomicAdd(&cnt[g], 1.f);
    }
}

// out[g] = (pooled[g,:]/max(cnt,1)) . lin_W + lin_b   — one wave per graph
__global__ __launch_bounds__(64) void final_kernel(const float* __restrict__ pooled,
                                                   const float* __restrict__ cnt,
                                                   const float* __restrict__ lin_W,
                                                   const float* __restrict__ lin_b,
                                                   float* __restrict__ out) {
    int g = blockIdx.x, d = threadIdx.x;
    float v = pooled[g * HD + d] / fmaxf(cnt[g], 1.f) * lin_W[d];
#pragma unroll
    for (int off = 32; off > 0; off >>= 1) v += __shfl_down(v, off, 64);
    if (d == 0) out[g] = v + lin_b[0];
}

// ---------------------------------------------------------------------------
extern "C" void kernel_launch(void* const* d_in, const int* in_sizes, int n_in,
                              void* d_out, int out_size, void* d_ws, size_t ws_size,
                              hipStream_t stream) {
    const float* x     = (const float*)d_in[0];
    const float* W1    = (const float*)d_in[1];
    const float* b1    = (const float*)d_in[2];
    const float* W2    = (const float*)d_in[3];
    const float* b2    = (const float*)d_in[4];
    const float* W3    = (const float*)d_in[5];
    const float* b3    = (const float*)d_in[6];
    const float* lin_W = (const float*)d_in[7];
    const float* lin_b = (const float*)d_in[8];
    const int* edge_index = (const int*)d_in[9];   // [2, NE]: row then col
    const int* batch      = (const int*)d_in[10];
    const int* row = edge_index;
    const int* col = edge_index + NE;
    float* out = (float*)d_out;

    // workspace layout: [deg int NN][pooled NG*HD][cnt NG][dinv NN][h][A][B]
    int*   deg    = (int*)d_ws;
    float* pooled = (float*)(deg + NN);
    float* cnt    = pooled + NG * HD;
    float* dinv   = cnt + NG;
    float* h      = dinv + NN;
    float* A      = h + (size_t)NN * HD;
    float* B      = A + (size_t)NN * HD;

    const int ZN = NN + NG * HD + NG;  // deg|pooled|cnt contiguous
    zero_kernel<<<(ZN + 255) / 256, 256, 0, stream>>>(deg, ZN);
    deg_kernel<<<(NE + 255) / 256, 256, 0, stream>>>(col, deg);
    dinv_kernel<<<(NN + 255) / 256, 256, 0, stream>>>(deg, dinv);

    const int GEMM_BLOCKS = NN / 16;            // 3125, exact
    const int EW_BLOCKS   = NE * 64 / 256;      // 200000
    const int NW_BLOCKS   = NN * 64 / 256;      // 12500

    // Layer 1: x -> A
    gemm64<<<GEMM_BLOCKS, 256, 0, stream>>>(x, W1, h, 0);
    init_out<<<NW_BLOCKS, 256, 0, stream>>>(A, h, dinv, b1);
    edge_scatter<<<EW_BLOCKS, 256, 0, stream>>>(A, h, row, col, dinv);

    // Layer 2: relu(A) -> B
    gemm64<<<GEMM_BLOCKS, 256, 0, stream>>>(A, W2, h, 1);
    init_out<<<NW_BLOCKS, 256, 0, stream>>>(B, h, dinv, b2);
    edge_scatter<<<EW_BLOCKS, 256, 0, stream>>>(B, h, row, col, dinv);

    // Layer 3: relu(B) -> A  (no relu on output)
    gemm64<<<GEMM_BLOCKS, 256, 0, stream>>>(B, W3, h, 1);
    init_out<<<NW_BLOCKS, 256, 0, stream>>>(A, h, dinv, b3);
    edge_scatter<<<EW_BLOCKS, 256, 0, stream>>>(A, h, row, col, dinv);

    // Pool + head
    pool_kernel<<<NW_BLOCKS, 256, 0, stream>>>(A, batch, pooled, cnt);
    final_kernel<<<NG, 64, 0, stream>>>(pooled, cnt, lin_W, lin_b, out);
}

// Round 2
// 466.781 us; speedup vs baseline: 1.6977x; 1.6977x over previous
//
#include <hip/hip_runtime.h>

// Problem constants (fixed by the reference file)
#define NN 50000     // nodes
#define NE 800000    // edges
#define HD 64        // feature dim (in and hidden)
#define NG 512       // graphs

// ---------------------------------------------------------------------------
__global__ void zero_kernel(int* __restrict__ p, int n) {
    int i = blockIdx.x * blockDim.x + threadIdx.x;
    if (i < n) p[i] = 0;
}

// degree over aggregation targets (col); self-loop handled as +1 in dinv
__global__ void deg_kernel(const int* __restrict__ col, int* __restrict__ deg) {
    int e = blockIdx.x * blockDim.x + threadIdx.x;
    if (e < NE) atomicAdd(&deg[col[e]], 1);
}

__global__ void dinv_kernel(const int* __restrict__ deg, float* __restrict__ dinv) {
    int i = blockIdx.x * blockDim.x + threadIdx.x;
    if (i < NN) dinv[i] = rsqrtf((float)(deg[i] + 1));  // +1 self-loop
}

// per-graph node counts (for mean pool)
__global__ void cnt_kernel(const int* __restrict__ batch, float* __restrict__ cnt) {
    int i = blockIdx.x * blockDim.x + threadIdx.x;
    if (i < NN) atomicAdd(&cnt[batch[i]], 1.f);
}

// single-block exclusive scan of deg[0..NN) -> rowptr[0..NN]
__global__ __launch_bounds__(1024) void scan_kernel(const int* __restrict__ deg,
                                                    int* __restrict__ rowptr) {
    __shared__ int wsum[16];
    __shared__ int carry_s;
    int tid = threadIdx.x, lane = tid & 63, wid = tid >> 6;
    if (tid == 0) carry_s = 0;
    __syncthreads();
    for (int base = 0; base < NN; base += 1024) {
        int i = base + tid;
        int v = (i < NN) ? deg[i] : 0;
        int inc = v;
#pragma unroll
        for (int off = 1; off < 64; off <<= 1) {
            int t = __shfl_up(inc, off, 64);
            if (lane >= off) inc += t;
        }
        if (lane == 63) wsum[wid] = inc;
        __syncthreads();
        int carry = carry_s;
        __syncthreads();  // all read carry before wave0 updates it
        if (wid == 0) {
            int wv = (lane < 16) ? wsum[lane] : 0;
            int winc = wv;
#pragma unroll
            for (int off = 1; off < 16; off <<= 1) {
                int t = __shfl_up(winc, off, 64);
                if (lane >= off) winc += t;
            }
            if (lane < 16) wsum[lane] = winc - wv;          // exclusive wave offset
            if (lane == 15) carry_s = carry + winc;         // add chunk total
        }
        __syncthreads();
        if (i < NN) rowptr[i] = carry + wsum[wid] + inc - v; // exclusive scan
        __syncthreads();  // wsum reused next chunk
    }
    if (tid == 0) rowptr[NN] = carry_s;
}

// scatter edges into CSR slots; precompute per-edge weight
__global__ void fill_csr(const int* __restrict__ row, const int* __restrict__ col,
                         const float* __restrict__ dinv, const int* __restrict__ rowptr,
                         int* __restrict__ cursor, int* __restrict__ csr_src,
                         float* __restrict__ csr_w) {
    int e = blockIdx.x * blockDim.x + threadIdx.x;
    if (e < NE) {
        int c = col[e], r = row[e];
        int pos = rowptr[c] + atomicAdd(&cursor[c], 1);
        csr_src[pos] = r;
        csr_w[pos] = dinv[r] * dinv[c];
    }
}

// ---------------------------------------------------------------------------
// h = maybe_relu(in) @ W    in: [NN,64], W: [64,64].  NN = 3125 * 16 exactly.
__global__ __launch_bounds__(256) void gemm64(const float* __restrict__ in,
                                              const float* __restrict__ W,
                                              float* __restrict__ out, int relu) {
    __shared__ float Ws[64][64];   // 16 KB
    __shared__ float Is[16][64];   // 4 KB
    int t = threadIdx.x;
    for (int i = t; i < 64 * 64; i += 256) Ws[i >> 6][i & 63] = W[i];
    int row0 = blockIdx.x * 16;
    for (int i = t; i < 16 * 64; i += 256) {
        float v = in[(row0 + (i >> 6)) * HD + (i & 63)];
        Is[i >> 6][i & 63] = relu ? fmaxf(v, 0.f) : v;
    }
    __syncthreads();
    int c = t & 63, r4 = t >> 6;
    float a0 = 0.f, a1 = 0.f, a2 = 0.f, a3 = 0.f;
#pragma unroll
    for (int k = 0; k < 64; ++k) {
        float w = Ws[k][c];
        a0 += Is[r4 + 0][k] * w;
        a1 += Is[r4 + 4][k] * w;
        a2 += Is[r4 + 8][k] * w;
        a3 += Is[r4 + 12][k] * w;
    }
    out[(row0 + r4 + 0) * HD + c] = a0;
    out[(row0 + r4 + 4) * HD + c] = a1;
    out[(row0 + r4 + 8) * HD + c] = a2;
    out[(row0 + r4 + 12) * HD + c] = a3;
}

// ---------------------------------------------------------------------------
// CSR gather: one wave per node, lane = channel.
// acc = dinv^2*h[i] + b + sum_j w_j*h[src_j]; either store or pool-atomic.
template <bool POOL>
__global__ __launch_bounds__(256) void gather(const float* __restrict__ h,
                                              const int* __restrict__ rowptr,
                                              const int* __restrict__ csr_src,
                                              const float* __restrict__ csr_w,
                                              const float* __restrict__ dinv,
                                              const float* __restrict__ b,
                                              float* __restrict__ out,
                                              const int* __restrict__ batch,
                                              float* __restrict__ pooled) {
    int node = blockIdx.x * 4 + (threadIdx.x >> 6);   // 4 waves/block
    int d = threadIdx.x & 63;
    if (node >= NN) return;
    int s = rowptr[node], e = rowptr[node + 1];
    float di = dinv[node];
    float acc = di * di * h[(size_t)node * HD + d] + b[d];
    int j = s;
    for (; j + 1 < e; j += 2) {
        int s0 = csr_src[j], s1 = csr_src[j + 1];
        float w0 = csr_w[j], w1 = csr_w[j + 1];
        float h0 = h[(size_t)s0 * HD + d];
        float h1 = h[(size_t)s1 * HD + d];
        acc += w0 * h0 + w1 * h1;
    }
    if (j < e) acc += csr_w[j] * h[(size_t)csr_src[j] * HD + d];
    if (POOL) {
        int g = batch[node];
        atomicAdd(&pooled[g * HD + d], acc);
    } else {
        out[(size_t)node * HD + d] = acc;
    }
}

// out[g] = (pooled[g,:]/max(cnt,1)) . lin_W + lin_b   — one wave per graph
__global__ __launch_bounds__(64) void final_kernel(const float* __restrict__ pooled,
                                                   const float* __restrict__ cnt,
                                                   const float* __restrict__ lin_W,
                                                   const float* __restrict__ lin_b,
                                                   float* __restrict__ out) {
    int g = blockIdx.x, d = threadIdx.x;
    float v = pooled[g * HD + d] / fmaxf(cnt[g], 1.f) * lin_W[d];
#pragma unroll
    for (int off = 32; off > 0; off >>= 1) v += __shfl_down(v, off, 64);
    if (d == 0) out[g] = v + lin_b[0];
}

// ---------------------------------------------------------------------------
extern "C" void kernel_launch(void* const* d_in, const int* in_sizes, int n_in,
                              void* d_out, int out_size, void* d_ws, size_t ws_size,
                              hipStream_t stream) {
    const float* x     = (const float*)d_in[0];
    const float* W1    = (const float*)d_in[1];
    const float* b1    = (const float*)d_in[2];
    const float* W2    = (const float*)d_in[3];
    const float* b2    = (const float*)d_in[4];
    const float* W3    = (const float*)d_in[5];
    const float* b3    = (const float*)d_in[6];
    const float* lin_W = (const float*)d_in[7];
    const float* lin_b = (const float*)d_in[8];
    const int* edge_index = (const int*)d_in[9];   // [2, NE]: row then col
    const int* batch      = (const int*)d_in[10];
    const int* row = edge_index;
    const int* col = edge_index + NE;
    float* out = (float*)d_out;

    // workspace layout (4B units):
    // [deg NN][cursor NN][pooled NG*HD][cnt NG][dinv NN][rowptr NN+1]
    // [csr_src NE][csr_w NE][h NN*HD][A NN*HD]
    int*   deg     = (int*)d_ws;
    int*   cursor  = deg + NN;
    float* pooled  = (float*)(cursor + NN);
    float* cnt     = pooled + NG * HD;
    float* dinv    = cnt + NG;
    int*   rowptr  = (int*)(dinv + NN);
    int*   csr_src = rowptr + NN + 1;
    float* csr_w   = (float*)(csr_src + NE);
    float* h       = csr_w + NE;
    float* A       = h + (size_t)NN * HD;

    // zero deg|cursor|pooled|cnt (contiguous)
    const int ZN = NN + NN + NG * HD + NG;
    zero_kernel<<<(ZN + 255) / 256, 256, 0, stream>>>(deg, ZN);
    deg_kernel<<<(NE + 255) / 256, 256, 0, stream>>>(col, deg);
    dinv_kernel<<<(NN + 255) / 256, 256, 0, stream>>>(deg, dinv);
    cnt_kernel<<<(NN + 255) / 256, 256, 0, stream>>>(batch, cnt);
    scan_kernel<<<1, 1024, 0, stream>>>(deg, rowptr);
    fill_csr<<<(NE + 255) / 256, 256, 0, stream>>>(row, col, dinv, rowptr,
                                                   cursor, csr_src, csr_w);

    const int GEMM_BLOCKS = NN / 16;              // 3125, exact
    const int GB = (NN + 3) / 4;                  // gather blocks (4 nodes each)

    // Layer 1: x -> h -> A
    gemm64<<<GEMM_BLOCKS, 256, 0, stream>>>(x, W1, h, 0);
    gather<false><<<GB, 256, 0, stream>>>(h, rowptr, csr_src, csr_w, dinv, b1,
                                          A, batch, pooled);
    // Layer 2: relu(A) -> h -> A
    gemm64<<<GEMM_BLOCKS, 256, 0, stream>>>(A, W2, h, 1);
    gather<false><<<GB, 256, 0, stream>>>(h, rowptr, csr_src, csr_w, dinv, b2,
                                          A, batch, pooled);
    // Layer 3: relu(A) -> h -> pooled (fused)
    gemm64<<<GEMM_BLOCKS, 256, 0, stream>>>(A, W3, h, 1);
    gather<true><<<GB, 256, 0, stream>>>(h, rowptr, csr_src, csr_w, dinv, b3,
                                         nullptr, batch, pooled);

    final_kernel<<<NG, 64, 0, stream>>>(pooled, cnt, lin_W, lin_b, out);
}

// Round 3
// 422.845 us; speedup vs baseline: 1.8741x; 1.1039x over previous
//
#include <hip/hip_runtime.h>

// Problem constants (fixed by the reference file)
#define NN 50000     // nodes
#define NE 800000    // edges
#define HD 64        // feature dim (in and hidden)
#define NG 512       // graphs
#define NB 196       // scan blocks: ceil(NN/256)

// ---------------------------------------------------------------------------
__global__ void zero_kernel(int* __restrict__ p, int n) {
    int i = blockIdx.x * blockDim.x + threadIdx.x;
    if (i < n) p[i] = 0;
}

// degree over aggregation targets + per-graph node counts, fused
__global__ void deg_cnt_kernel(const int* __restrict__ col, int* __restrict__ deg,
                               const int* __restrict__ batch, float* __restrict__ cnt) {
    int i = blockIdx.x * blockDim.x + threadIdx.x;
    if (i < NE) atomicAdd(&deg[col[i]], 1);
    if (i < NN) atomicAdd(&cnt[batch[i]], 1.f);
}

__global__ void dinv_kernel(const int* __restrict__ deg, float* __restrict__ dinv) {
    int i = blockIdx.x * blockDim.x + threadIdx.x;
    if (i < NN) dinv[i] = rsqrtf((float)(deg[i] + 1));  // +1 self-loop
}

// ---- 3-stage scan: deg -> rowptr (exclusive) ------------------------------
__global__ __launch_bounds__(256) void block_reduce(const int* __restrict__ deg,
                                                    int* __restrict__ bsum) {
    __shared__ int ws[4];
    int tid = threadIdx.x, lane = tid & 63, wid = tid >> 6;
    int i = blockIdx.x * 256 + tid;
    int v = (i < NN) ? deg[i] : 0;
#pragma unroll
    for (int off = 32; off > 0; off >>= 1) v += __shfl_down(v, off, 64);
    if (lane == 0) ws[wid] = v;
    __syncthreads();
    if (tid == 0) bsum[blockIdx.x] = ws[0] + ws[1] + ws[2] + ws[3];
}

__global__ __launch_bounds__(64) void scan_bsum(int* __restrict__ bsum) {
    int lane = threadIdx.x;
    int carry = 0;
    for (int base = 0; base < NB; base += 64) {
        int i = base + lane;
        int v = (i < NB) ? bsum[i] : 0;
        int inc = v;
#pragma unroll
        for (int off = 1; off < 64; off <<= 1) {
            int t = __shfl_up(inc, off, 64);
            if (lane >= off) inc += t;
        }
        if (i < NB) bsum[i] = carry + inc - v;  // exclusive
        carry += __shfl(inc, 63, 64);
    }
}

__global__ __launch_bounds__(256) void block_scan(const int* __restrict__ deg,
                                                  const int* __restrict__ bsum,
                                                  int* __restrict__ rowptr) {
    __shared__ int ws[4];
    int tid = threadIdx.x, lane = tid & 63, wid = tid >> 6;
    int i = blockIdx.x * 256 + tid;
    int v = (i < NN) ? deg[i] : 0;
    int inc = v;
#pragma unroll
    for (int off = 1; off < 64; off <<= 1) {
        int t = __shfl_up(inc, off, 64);
        if (lane >= off) inc += t;
    }
    if (lane == 63) ws[wid] = inc;
    __syncthreads();
    int woff = 0;
    for (int k = 0; k < wid; ++k) woff += ws[k];
    if (i < NN) rowptr[i] = bsum[blockIdx.x] + woff + inc - v;
    if (blockIdx.x == 0 && tid == 0) rowptr[NN] = NE;
}

// scatter edges into CSR slots; (src, weight) interleaved as int2
__global__ void fill_csr(const int* __restrict__ row, const int* __restrict__ col,
                         const float* __restrict__ dinv, const int* __restrict__ rowptr,
                         int* __restrict__ cursor, int2* __restrict__ ew) {
    int e = blockIdx.x * blockDim.x + threadIdx.x;
    if (e < NE) {
        int c = col[e], r = row[e];
        int pos = rowptr[c] + atomicAdd(&cursor[c], 1);
        float w = dinv[r] * dinv[c];
        ew[pos] = make_int2(r, __float_as_int(w));
    }
}

// ---------------------------------------------------------------------------
// h = maybe_relu(in) @ W    in: [NN,64], W: [64,64].  NN = 3125 * 16 exactly.
__global__ __launch_bounds__(256) void gemm64(const float* __restrict__ in,
                                              const float* __restrict__ W,
                                              float* __restrict__ out, int relu) {
    __shared__ float Ws[64][64];   // 16 KB
    __shared__ float Is[16][64];   // 4 KB
    int t = threadIdx.x;
    for (int i = t; i < 64 * 64; i += 256) Ws[i >> 6][i & 63] = W[i];
    int row0 = blockIdx.x * 16;
    for (int i = t; i < 16 * 64; i += 256) {
        float v = in[(row0 + (i >> 6)) * HD + (i & 63)];
        Is[i >> 6][i & 63] = relu ? fmaxf(v, 0.f) : v;
    }
    __syncthreads();
    int c = t & 63, r4 = t >> 6;
    float a0 = 0.f, a1 = 0.f, a2 = 0.f, a3 = 0.f;
#pragma unroll
    for (int k = 0; k < 64; ++k) {
        float w = Ws[k][c];
        a0 += Is[r4 + 0][k] * w;
        a1 += Is[r4 + 4][k] * w;
        a2 += Is[r4 + 8][k] * w;
        a3 += Is[r4 + 12][k] * w;
    }
    out[(row0 + r4 + 0) * HD + c] = a0;
    out[(row0 + r4 + 4) * HD + c] = a1;
    out[(row0 + r4 + 8) * HD + c] = a2;
    out[(row0 + r4 + 12) * HD + c] = a3;
}

// ---------------------------------------------------------------------------
// CSR gather, float4 channels: 16 lanes/node (4 ch each), 4 nodes/wave,
// 16 nodes/block. acc = dinv^2*h[i] + b + sum_j w_j*h[src_j].
template <bool POOL>
__global__ __launch_bounds__(256) void gather4(const float* __restrict__ h,
                                               const int* __restrict__ rowptr,
                                               const int2* __restrict__ ew,
                                               const float* __restrict__ dinv,
                                               const float* __restrict__ b,
                                               float* __restrict__ out,
                                               const int* __restrict__ batch,
                                               float* __restrict__ pooled) {
    int tid = threadIdx.x, lane = tid & 63, wid = tid >> 6;
    int sub = lane >> 4, q = lane & 15;        // node-in-wave, float4-channel
    int node = blockIdx.x * 16 + wid * 4 + sub;  // NN = 3125*16 exact
    const float4* h4 = (const float4*)h;
    int s = rowptr[node], e = rowptr[node + 1];
    float di = dinv[node], dd = di * di;
    float4 hv = h4[node * 16 + q];
    float4 b4 = ((const float4*)b)[q];
    float4 acc;
    acc.x = dd * hv.x + b4.x;
    acc.y = dd * hv.y + b4.y;
    acc.z = dd * hv.z + b4.z;
    acc.w = dd * hv.w + b4.w;
    int j = s, e4 = s + ((e - s) & ~3);
    for (; j < e4; j += 4) {
        int2 p0 = ew[j], p1 = ew[j + 1], p2 = ew[j + 2], p3 = ew[j + 3];
        float4 h0 = h4[p0.x * 16 + q];
        float4 h1 = h4[p1.x * 16 + q];
        float4 h2 = h4[p2.x * 16 + q];
        float4 h3 = h4[p3.x * 16 + q];
        float w0 = __int_as_float(p0.y), w1 = __int_as_float(p1.y);
        float w2 = __int_as_float(p2.y), w3 = __int_as_float(p3.y);
        acc.x += w0 * h0.x + w1 * h1.x + w2 * h2.x + w3 * h3.x;
        acc.y += w0 * h0.y + w1 * h1.y + w2 * h2.y + w3 * h3.y;
        acc.z += w0 * h0.z + w1 * h1.z + w2 * h2.z + w3 * h3.z;
        acc.w += w0 * h0.w + w1 * h1.w + w2 * h2.w + w3 * h3.w;
    }
    for (; j < e; ++j) {
        int2 p = ew[j];
        float4 hj = h4[p.x * 16 + q];
        float w = __int_as_float(p.y);
        acc.x += w * hj.x;
        acc.y += w * hj.y;
        acc.z += w * hj.z;
        acc.w += w * hj.w;
    }
    if (POOL) {
        int g = batch[node];
        float* pg = &pooled[g * HD + q * 4];
        atomicAdd(pg + 0, acc.x);
        atomicAdd(pg + 1, acc.y);
        atomicAdd(pg + 2, acc.z);
        atomicAdd(pg + 3, acc.w);
    } else {
        ((float4*)out)[node * 16 + q] = acc;
    }
}

// out[g] = (pooled[g,:]/max(cnt,1)) . lin_W + lin_b   — one wave per graph
__global__ __launch_bounds__(64) void final_kernel(const float* __restrict__ pooled,
                                                   const float* __restrict__ cnt,
                                                   const float* __restrict__ lin_W,
                                                   const float* __restrict__ lin_b,
                                                   float* __restrict__ out) {
    int g = blockIdx.x, d = threadIdx.x;
    float v = pooled[g * HD + d] / fmaxf(cnt[g], 1.f) * lin_W[d];
#pragma unroll
    for (int off = 32; off > 0; off >>= 1) v += __shfl_down(v, off, 64);
    if (d == 0) out[g] = v + lin_b[0];
}

// ---------------------------------------------------------------------------
extern "C" void kernel_launch(void* const* d_in, const int* in_sizes, int n_in,
                              void* d_out, int out_size, void* d_ws, size_t ws_size,
                              hipStream_t stream) {
    const float* x     = (const float*)d_in[0];
    const float* W1    = (const float*)d_in[1];
    const float* b1    = (const float*)d_in[2];
    const float* W2    = (const float*)d_in[3];
    const float* b2    = (const float*)d_in[4];
    const float* W3    = (const float*)d_in[5];
    const float* b3    = (const float*)d_in[6];
    const float* lin_W = (const float*)d_in[7];
    const float* lin_b = (const float*)d_in[8];
    const int* edge_index = (const int*)d_in[9];   // [2, NE]: row then col
    const int* batch      = (const int*)d_in[10];
    const int* row = edge_index;
    const int* col = edge_index + NE;
    float* out = (float*)d_out;

    // workspace layout (4B units), big aligned arrays first:
    // [h NN*HD][A NN*HD][ew 2*NE][rowptr NN+2][deg NN][cursor NN]
    // [pooled NG*HD][cnt NG][dinv NN][bsum 256]
    float* h       = (float*)d_ws;
    float* A       = h + (size_t)NN * HD;
    int2*  ew      = (int2*)(A + (size_t)NN * HD);
    int*   rowptr  = (int*)(ew + NE);
    int*   deg     = rowptr + NN + 2;
    int*   cursor  = deg + NN;
    float* pooled  = (float*)(cursor + NN);
    float* cnt     = pooled + NG * HD;
    float* dinv    = cnt + NG;
    int*   bsum    = (int*)(dinv + NN);

    // zero deg|cursor|pooled|cnt (contiguous)
    const int ZN = NN + NN + NG * HD + NG;
    zero_kernel<<<(ZN + 255) / 256, 256, 0, stream>>>(deg, ZN);
    deg_cnt_kernel<<<(NE + 255) / 256, 256, 0, stream>>>(col, deg, batch, cnt);
    dinv_kernel<<<(NN + 255) / 256, 256, 0, stream>>>(deg, dinv);
    block_reduce<<<NB, 256, 0, stream>>>(deg, bsum);
    scan_bsum<<<1, 64, 0, stream>>>(bsum);
    block_scan<<<NB, 256, 0, stream>>>(deg, bsum, rowptr);
    fill_csr<<<(NE + 255) / 256, 256, 0, stream>>>(row, col, dinv, rowptr,
                                                   cursor, ew);

    const int GEMM_BLOCKS = NN / 16;   // 3125, exact
    const int GB = NN / 16;            // gather4 blocks (16 nodes each), exact

    // Layer 1: x -> h -> A
    gemm64<<<GEMM_BLOCKS, 256, 0, stream>>>(x, W1, h, 0);
    gather4<false><<<GB, 256, 0, stream>>>(h, rowptr, ew, dinv, b1, A, batch, pooled);
    // Layer 2: relu(A) -> h -> A
    gemm64<<<GEMM_BLOCKS, 256, 0, stream>>>(A, W2, h, 1);
    gather4<false><<<GB, 256, 0, stream>>>(h, rowptr, ew, dinv, b2, A, batch, pooled);
    // Layer 3: relu(A) -> h -> pooled (fused)
    gemm64<<<GEMM_BLOCKS, 256, 0, stream>>>(A, W3, h, 1);
    gather4<true><<<GB, 256, 0, stream>>>(h, rowptr, ew, dinv, b3, nullptr, batch, pooled);

    final_kernel<<<NG, 64, 0, stream>>>(pooled, cnt, lin_W, lin_b, out);
}

// Round 4
// 369.557 us; speedup vs baseline: 2.1443x; 1.1442x over previous
//
#include <hip/hip_runtime.h>
#include <hip/hip_fp16.h>

// Problem constants (fixed by the reference file)
#define NN 50000     // nodes
#define NE 800000    // edges
#define HD 64        // feature dim (in and hidden)
#define NG 512       // graphs
#define NB 196       // scan blocks: ceil(NN/256)

// ---------------------------------------------------------------------------
__global__ void zero_kernel(int* __restrict__ p, int n) {
    int i = blockIdx.x * blockDim.x + threadIdx.x;
    if (i < n) p[i] = 0;
}

// degree over aggregation targets + per-graph node counts, fused
__global__ void deg_cnt_kernel(const int* __restrict__ col, int* __restrict__ deg,
                               const int* __restrict__ batch, float* __restrict__ cnt) {
    int i = blockIdx.x * blockDim.x + threadIdx.x;
    if (i < NE) atomicAdd(&deg[col[i]], 1);
    if (i < NN) atomicAdd(&cnt[batch[i]], 1.f);
}

__global__ void dinv_kernel(const int* __restrict__ deg, float* __restrict__ dinv) {
    int i = blockIdx.x * blockDim.x + threadIdx.x;
    if (i < NN) dinv[i] = rsqrtf((float)(deg[i] + 1));  // +1 self-loop
}

// ---- 3-stage scan: deg -> rowptr (exclusive) ------------------------------
__global__ __launch_bounds__(256) void block_reduce(const int* __restrict__ deg,
                                                    int* __restrict__ bsum) {
    __shared__ int ws[4];
    int tid = threadIdx.x, lane = tid & 63, wid = tid >> 6;
    int i = blockIdx.x * 256 + tid;
    int v = (i < NN) ? deg[i] : 0;
#pragma unroll
    for (int off = 32; off > 0; off >>= 1) v += __shfl_down(v, off, 64);
    if (lane == 0) ws[wid] = v;
    __syncthreads();
    if (tid == 0) bsum[blockIdx.x] = ws[0] + ws[1] + ws[2] + ws[3];
}

__global__ __launch_bounds__(64) void scan_bsum(int* __restrict__ bsum) {
    int lane = threadIdx.x;
    int carry = 0;
    for (int base = 0; base < NB; base += 64) {
        int i = base + lane;
        int v = (i < NB) ? bsum[i] : 0;
        int inc = v;
#pragma unroll
        for (int off = 1; off < 64; off <<= 1) {
            int t = __shfl_up(inc, off, 64);
            if (lane >= off) inc += t;
        }
        if (i < NB) bsum[i] = carry + inc - v;  // exclusive
        carry += __shfl(inc, 63, 64);
    }
}

__global__ __launch_bounds__(256) void block_scan(const int* __restrict__ deg,
                                                  const int* __restrict__ bsum,
                                                  int* __restrict__ rowptr) {
    __shared__ int ws[4];
    int tid = threadIdx.x, lane = tid & 63, wid = tid >> 6;
    int i = blockIdx.x * 256 + tid;
    int v = (i < NN) ? deg[i] : 0;
    int inc = v;
#pragma unroll
    for (int off = 1; off < 64; off <<= 1) {
        int t = __shfl_up(inc, off, 64);
        if (lane >= off) inc += t;
    }
    if (lane == 63) ws[wid] = inc;
    __syncthreads();
    int woff = 0;
    for (int k = 0; k < wid; ++k) woff += ws[k];
    if (i < NN) rowptr[i] = bsum[blockIdx.x] + woff + inc - v;
    if (blockIdx.x == 0 && tid == 0) rowptr[NN] = NE;
}

// scatter edges into CSR slots; (src, weight) interleaved as int2
__global__ void fill_csr(const int* __restrict__ row, const int* __restrict__ col,
                         const float* __restrict__ dinv, const int* __restrict__ rowptr,
                         int* __restrict__ cursor, int2* __restrict__ ew) {
    int e = blockIdx.x * blockDim.x + threadIdx.x;
    if (e < NE) {
        int c = col[e], r = row[e];
        int pos = rowptr[c] + atomicAdd(&cursor[c], 1);
        float w = dinv[r] * dinv[c];
        ew[pos] = make_int2(r, __float_as_int(w));
    }
}

// ---------------------------------------------------------------------------
// h16 = in @ W    in: fp32 [NN,64], W: fp32 [64,64], out fp16. (layer 1)
__global__ __launch_bounds__(256) void gemm64_f32(const float* __restrict__ in,
                                                  const float* __restrict__ W,
                                                  __half* __restrict__ out) {
    __shared__ float Ws[64][64];   // 16 KB
    __shared__ float Is[16][64];   // 4 KB
    int t = threadIdx.x;
    for (int i = t; i < 64 * 64; i += 256) Ws[i >> 6][i & 63] = W[i];
    int row0 = blockIdx.x * 16;
    for (int i = t; i < 16 * 64; i += 256)
        Is[i >> 6][i & 63] = in[(row0 + (i >> 6)) * HD + (i & 63)];
    __syncthreads();
    int c = t & 63, r4 = t >> 6;
    float a0 = 0.f, a1 = 0.f, a2 = 0.f, a3 = 0.f;
#pragma unroll
    for (int k = 0; k < 64; ++k) {
        float w = Ws[k][c];
        a0 += Is[r4 + 0][k] * w;
        a1 += Is[r4 + 4][k] * w;
        a2 += Is[r4 + 8][k] * w;
        a3 += Is[r4 + 12][k] * w;
    }
    out[(row0 + r4 + 0) * HD + c] = __float2half(a0);
    out[(row0 + r4 + 4) * HD + c] = __float2half(a1);
    out[(row0 + r4 + 8) * HD + c] = __float2half(a2);
    out[(row0 + r4 + 12) * HD + c] = __float2half(a3);
}

// h16 = relu(in16) @ W   (layers 2,3)
__global__ __launch_bounds__(256) void gemm64_f16(const __half* __restrict__ in,
                                                  const float* __restrict__ W,
                                                  __half* __restrict__ out) {
    __shared__ float Ws[64][64];
    __shared__ float Is[16][64];
    int t = threadIdx.x;
    for (int i = t; i < 64 * 64; i += 256) Ws[i >> 6][i & 63] = W[i];
    int row0 = blockIdx.x * 16;
    const __half2* in2 = (const __half2*)(in + (size_t)row0 * HD);
    for (int i = t; i < 16 * 32; i += 256) {
        float2 v = __half22float2(in2[i]);
        int r = i >> 5, c2 = (i & 31) * 2;
        Is[r][c2]     = fmaxf(v.x, 0.f);
        Is[r][c2 + 1] = fmaxf(v.y, 0.f);
    }
    __syncthreads();
    int c = t & 63, r4 = t >> 6;
    float a0 = 0.f, a1 = 0.f, a2 = 0.f, a3 = 0.f;
#pragma unroll
    for (int k = 0; k < 64; ++k) {
        float w = Ws[k][c];
        a0 += Is[r4 + 0][k] * w;
        a1 += Is[r4 + 4][k] * w;
        a2 += Is[r4 + 8][k] * w;
        a3 += Is[r4 + 12][k] * w;
    }
    out[(row0 + r4 + 0) * HD + c] = __float2half(a0);
    out[(row0 + r4 + 4) * HD + c] = __float2half(a1);
    out[(row0 + r4 + 8) * HD + c] = __float2half(a2);
    out[(row0 + r4 + 12) * HD + c] = __float2half(a3);
}

// ---------------------------------------------------------------------------
// CSR gather, fp16 features: ONE node per wave. Half-wave hh in {0,1} handles
// edge stream s+hh, s+hh+2, ...; 32 lanes x half2 = full 128B row per edge.
// Unroll 4 pairs -> 8 edges, 8 outstanding loads. fp32 accumulate.
template <bool POOL>
__global__ __launch_bounds__(256) void gather_h16(const __half* __restrict__ h16,
                                                  const int* __restrict__ rowptr,
                                                  const int2* __restrict__ ew,
                                                  const float* __restrict__ dinv,
                                                  const float* __restrict__ b,
                                                  __half* __restrict__ out16,
                                                  const int* __restrict__ batch,
                                                  float* __restrict__ pooled) {
    int tid = threadIdx.x, lane = tid & 63, wid = tid >> 6;
    int hh = lane >> 5, c = lane & 31;          // half-wave id, half2 channel
    int node = blockIdx.x * 4 + wid;            // NN = 12500*4 exact
    const __half2* hv = (const __half2*)h16;
    int s = rowptr[node], e = rowptr[node + 1];
    float2 acc;
    if (hh == 0) {  // self-loop + bias only in half 0 (halves are summed later)
        float di = dinv[node], dd = di * di;
        float2 self = __half22float2(hv[node * 32 + c]);
        float2 bb = ((const float2*)b)[c];
        acc.x = dd * self.x + bb.x;
        acc.y = dd * self.y + bb.y;
    } else {
        acc.x = 0.f; acc.y = 0.f;
    }
    int nfull = (e - s) & ~7;
    int j = s + hh, jend = s + nfull;
    for (; j < jend; j += 8) {
        int2 p0 = ew[j], p1 = ew[j + 2], p2 = ew[j + 4], p3 = ew[j + 6];
        __half2 v0 = hv[p0.x * 32 + c];
        __half2 v1 = hv[p1.x * 32 + c];
        __half2 v2 = hv[p2.x * 32 + c];
        __half2 v3 = hv[p3.x * 32 + c];
        float w0 = __int_as_float(p0.y), w1 = __int_as_float(p1.y);
        float w2 = __int_as_float(p2.y), w3 = __int_as_float(p3.y);
        float2 f0 = __half22float2(v0), f1 = __half22float2(v1);
        float2 f2 = __half22float2(v2), f3 = __half22float2(v3);
        acc.x += w0 * f0.x + w1 * f1.x + w2 * f2.x + w3 * f3.x;
        acc.y += w0 * f0.y + w1 * f1.y + w2 * f2.y + w3 * f3.y;
    }
    for (; j < e; j += 2) {  // tail 0..7 edges, per-lane predicate
        int2 p = ew[j];
        __half2 v = hv[p.x * 32 + c];
        float w = __int_as_float(p.y);
        float2 f = __half22float2(v);
        acc.x += w * f.x;
        acc.y += w * f.y;
    }
    // combine the two half-wave partial sums (lane L ^ 32 holds same channels)
    acc.x += __shfl_xor(acc.x, 32, 64);
    acc.y += __shfl_xor(acc.y, 32, 64);
    if (hh == 0) {
        if (POOL) {
            int g = batch[node];
            atomicAdd(&pooled[g * HD + 2 * c], acc.x);
            atomicAdd(&pooled[g * HD + 2 * c + 1], acc.y);
        } else {
            ((__half2*)out16)[node * 32 + c] = __floats2half2_rn(acc.x, acc.y);
        }
    }
}

// out[g] = (pooled[g,:]/max(cnt,1)) . lin_W + lin_b   — one wave per graph
__global__ __launch_bounds__(64) void final_kernel(const float* __restrict__ pooled,
                                                   const float* __restrict__ cnt,
                                                   const float* __restrict__ lin_W,
                                                   const float* __restrict__ lin_b,
                                                   float* __restrict__ out) {
    int g = blockIdx.x, d = threadIdx.x;
    float v = pooled[g * HD + d] / fmaxf(cnt[g], 1.f) * lin_W[d];
#pragma unroll
    for (int off = 32; off > 0; off >>= 1) v += __shfl_down(v, off, 64);
    if (d == 0) out[g] = v + lin_b[0];
}

// ---------------------------------------------------------------------------
extern "C" void kernel_launch(void* const* d_in, const int* in_sizes, int n_in,
                              void* d_out, int out_size, void* d_ws, size_t ws_size,
                              hipStream_t stream) {
    const float* x     = (const float*)d_in[0];
    const float* W1    = (const float*)d_in[1];
    const float* b1    = (const float*)d_in[2];
    const float* W2    = (const float*)d_in[3];
    const float* b2    = (const float*)d_in[4];
    const float* W3    = (const float*)d_in[5];
    const float* b3    = (const float*)d_in[6];
    const float* lin_W = (const float*)d_in[7];
    const float* lin_b = (const float*)d_in[8];
    const int* edge_index = (const int*)d_in[9];   // [2, NE]: row then col
    const int* batch      = (const int*)d_in[10];
    const int* row = edge_index;
    const int* col = edge_index + NE;
    float* out = (float*)d_out;

    // workspace layout:
    // [h16 NN*HD half][A16 NN*HD half][ew NE int2][rowptr NN+2]
    // [deg NN][cursor NN][pooled NG*HD][cnt NG][dinv NN][bsum NB]
    __half* h16    = (__half*)d_ws;
    __half* A16    = h16 + (size_t)NN * HD;
    int2*   ew     = (int2*)(A16 + (size_t)NN * HD);
    int*    rowptr = (int*)(ew + NE);
    int*    deg    = rowptr + NN + 2;
    int*    cursor = deg + NN;
    float*  pooled = (float*)(cursor + NN);
    float*  cnt    = pooled + NG * HD;
    float*  dinv   = cnt + NG;
    int*    bsum   = (int*)(dinv + NN);

    // zero deg|cursor|pooled|cnt (contiguous)
    const int ZN = NN + NN + NG * HD + NG;
    zero_kernel<<<(ZN + 255) / 256, 256, 0, stream>>>(deg, ZN);
    deg_cnt_kernel<<<(NE + 255) / 256, 256, 0, stream>>>(col, deg, batch, cnt);
    dinv_kernel<<<(NN + 255) / 256, 256, 0, stream>>>(deg, dinv);
    block_reduce<<<NB, 256, 0, stream>>>(deg, bsum);
    scan_bsum<<<1, 64, 0, stream>>>(bsum);
    block_scan<<<NB, 256, 0, stream>>>(deg, bsum, rowptr);
    fill_csr<<<(NE + 255) / 256, 256, 0, stream>>>(row, col, dinv, rowptr,
                                                   cursor, ew);

    const int GEMM_BLOCKS = NN / 16;   // 3125, exact
    const int GB = NN / 4;             // gather blocks: 4 nodes (waves) each

    // Layer 1: x -> h16 -> A16
    gemm64_f32<<<GEMM_BLOCKS, 256, 0, stream>>>(x, W1, h16);
    gather_h16<false><<<GB, 256, 0, stream>>>(h16, rowptr, ew, dinv, b1, A16,
                                              batch, pooled);
    // Layer 2: relu(A16) -> h16 -> A16
    gemm64_f16<<<GEMM_BLOCKS, 256, 0, stream>>>(A16, W2, h16);
    gather_h16<false><<<GB, 256, 0, stream>>>(h16, rowptr, ew, dinv, b2, A16,
                                              batch, pooled);
    // Layer 3: relu(A16) -> h16 -> pooled (fused)
    gemm64_f16<<<GEMM_BLOCKS, 256, 0, stream>>>(A16, W3, h16);
    gather_h16<true><<<GB, 256, 0, stream>>>(h16, rowptr, ew, dinv, b3, nullptr,
                                             batch, pooled);

    final_kernel<<<NG, 64, 0, stream>>>(pooled, cnt, lin_W, lin_b, out);
}

// Round 5
// 327.973 us; speedup vs baseline: 2.4162x; 1.1268x over previous
//
#include <hip/hip_runtime.h>
#include <hip/hip_fp16.h>

// Problem constants (fixed by the reference file)
#define NN 50000     // nodes
#define NE 800000    // edges
#define HD 64        // feature dim (in and hidden)
#define NG 512       // graphs
#define NB 196       // scan blocks: ceil(NN/256)
#define GEMM_BLOCKS 3125   // NN/16
#define EDGE_BLOCKS 3125   // NE/256

// ---------------------------------------------------------------------------
__global__ void zero_kernel(int* __restrict__ p, int n) {
    int i = blockIdx.x * blockDim.x + threadIdx.x;
    if (i < n) p[i] = 0;
}

// ---------------------------------------------------------------------------
// Fused: blocks [0,GEMM_BLOCKS) do h16 = x @ W1 (fp32 in, fp16 out);
// blocks [GEMM_BLOCKS, +EDGE_BLOCKS) do the single atomic pass:
//   rank[e] = atomicAdd(&cursor[col[e]], 1)   (cursor ends up = deg)
//   cnt[batch[i]] += 1                         (graph node counts)
__global__ __launch_bounds__(256) void gemm1_rank(const float* __restrict__ x,
                                                  const float* __restrict__ W1,
                                                  __half* __restrict__ h16,
                                                  const int* __restrict__ col,
                                                  const int* __restrict__ batch,
                                                  int* __restrict__ cursor,
                                                  int* __restrict__ rank,
                                                  float* __restrict__ cnt) {
    if (blockIdx.x < GEMM_BLOCKS) {
        __shared__ float Ws[64][64];   // 16 KB
        __shared__ float Is[16][64];   // 4 KB
        int t = threadIdx.x;
        for (int i = t; i < 64 * 64; i += 256) Ws[i >> 6][i & 63] = W1[i];
        int row0 = blockIdx.x * 16;
        for (int i = t; i < 16 * 64; i += 256)
            Is[i >> 6][i & 63] = x[(row0 + (i >> 6)) * HD + (i & 63)];
        __syncthreads();
        int c = t & 63, r4 = t >> 6;
        float a0 = 0.f, a1 = 0.f, a2 = 0.f, a3 = 0.f;
#pragma unroll
        for (int k = 0; k < 64; ++k) {
            float w = Ws[k][c];
            a0 += Is[r4 + 0][k] * w;
            a1 += Is[r4 + 4][k] * w;
            a2 += Is[r4 + 8][k] * w;
            a3 += Is[r4 + 12][k] * w;
        }
        h16[(row0 + r4 + 0) * HD + c] = __float2half(a0);
        h16[(row0 + r4 + 4) * HD + c] = __float2half(a1);
        h16[(row0 + r4 + 8) * HD + c] = __float2half(a2);
        h16[(row0 + r4 + 12) * HD + c] = __float2half(a3);
    } else {
        int t = (blockIdx.x - GEMM_BLOCKS) * 256 + threadIdx.x;
        if (t < NE) rank[t] = atomicAdd(&cursor[col[t]], 1);
        if (t < NN) atomicAdd(&cnt[batch[t]], 1.f);
    }
}

// ---- 3-stage scan: deg(=cursor) -> rowptr (exclusive); dinv fused ---------
__global__ __launch_bounds__(256) void block_reduce(const int* __restrict__ deg,
                                                    int* __restrict__ bsum) {
    __shared__ int ws[4];
    int tid = threadIdx.x, lane = tid & 63, wid = tid >> 6;
    int i = blockIdx.x * 256 + tid;
    int v = (i < NN) ? deg[i] : 0;
#pragma unroll
    for (int off = 32; off > 0; off >>= 1) v += __shfl_down(v, off, 64);
    if (lane == 0) ws[wid] = v;
    __syncthreads();
    if (tid == 0) bsum[blockIdx.x] = ws[0] + ws[1] + ws[2] + ws[3];
}

__global__ __launch_bounds__(64) void scan_bsum(int* __restrict__ bsum) {
    int lane = threadIdx.x;
    int carry = 0;
    for (int base = 0; base < NB; base += 64) {
        int i = base + lane;
        int v = (i < NB) ? bsum[i] : 0;
        int inc = v;
#pragma unroll
        for (int off = 1; off < 64; off <<= 1) {
            int t = __shfl_up(inc, off, 64);
            if (lane >= off) inc += t;
        }
        if (i < NB) bsum[i] = carry + inc - v;  // exclusive
        carry += __shfl(inc, 63, 64);
    }
}

__global__ __launch_bounds__(256) void block_scan(const int* __restrict__ deg,
                                                  const int* __restrict__ bsum,
                                                  int* __restrict__ rowptr,
                                                  float* __restrict__ dinv) {
    __shared__ int ws[4];
    int tid = threadIdx.x, lane = tid & 63, wid = tid >> 6;
    int i = blockIdx.x * 256 + tid;
    int v = (i < NN) ? deg[i] : 0;
    int inc = v;
#pragma unroll
    for (int off = 1; off < 64; off <<= 1) {
        int t = __shfl_up(inc, off, 64);
        if (lane >= off) inc += t;
    }
    if (lane == 63) ws[wid] = inc;
    __syncthreads();
    int woff = 0;
    for (int k = 0; k < wid; ++k) woff += ws[k];
    if (i < NN) {
        rowptr[i] = bsum[blockIdx.x] + woff + inc - v;
        dinv[i] = rsqrtf((float)(v + 1));  // +1 self-loop
    }
    if (blockIdx.x == 0 && tid == 0) rowptr[NN] = NE;
}

// atomic-free CSR fill: pos = rowptr[col] + rank  (ranks unique per col)
__global__ void fill_csr(const int* __restrict__ row, const int* __restrict__ col,
                         const int* __restrict__ rank, const float* __restrict__ dinv,
                         const int* __restrict__ rowptr, int2* __restrict__ ew) {
    int e = blockIdx.x * blockDim.x + threadIdx.x;
    if (e < NE) {
        int c = col[e], r = row[e];
        int pos = rowptr[c] + rank[e];
        float w = dinv[r] * dinv[c];
        ew[pos] = make_int2(r, __float_as_int(w));
    }
}

// ---------------------------------------------------------------------------
// h16 = relu(in16) @ W   (layers 2,3)
__global__ __launch_bounds__(256) void gemm64_f16(const __half* __restrict__ in,
                                                  const float* __restrict__ W,
                                                  __half* __restrict__ out) {
    __shared__ float Ws[64][64];
    __shared__ float Is[16][64];
    int t = threadIdx.x;
    for (int i = t; i < 64 * 64; i += 256) Ws[i >> 6][i & 63] = W[i];
    int row0 = blockIdx.x * 16;
    const __half2* in2 = (const __half2*)(in + (size_t)row0 * HD);
    for (int i = t; i < 16 * 32; i += 256) {
        float2 v = __half22float2(in2[i]);
        int r = i >> 5, c2 = (i & 31) * 2;
        Is[r][c2]     = fmaxf(v.x, 0.f);
        Is[r][c2 + 1] = fmaxf(v.y, 0.f);
    }
    __syncthreads();
    int c = t & 63, r4 = t >> 6;
    float a0 = 0.f, a1 = 0.f, a2 = 0.f, a3 = 0.f;
#pragma unroll
    for (int k = 0; k < 64; ++k) {
        float w = Ws[k][c];
        a0 += Is[r4 + 0][k] * w;
        a1 += Is[r4 + 4][k] * w;
        a2 += Is[r4 + 8][k] * w;
        a3 += Is[r4 + 12][k] * w;
    }
    out[(row0 + r4 + 0) * HD + c] = __float2half(a0);
    out[(row0 + r4 + 4) * HD + c] = __float2half(a1);
    out[(row0 + r4 + 8) * HD + c] = __float2half(a2);
    out[(row0 + r4 + 12) * HD + c] = __float2half(a3);
}

// ---------------------------------------------------------------------------
// CSR gather, fp16 features: ONE node per wave. Half-wave hh in {0,1} handles
// edge stream s+hh, s+hh+2, ...; 32 lanes x half2 = full 128B row per edge.
// Unroll 4 pairs -> 8 edges, 8 outstanding loads. fp32 accumulate.
template <bool POOL>
__global__ __launch_bounds__(256) void gather_h16(const __half* __restrict__ h16,
                                                  const int* __restrict__ rowptr,
                                                  const int2* __restrict__ ew,
                                                  const float* __restrict__ dinv,
                                                  const float* __restrict__ b,
                                                  __half* __restrict__ out16,
                                                  const int* __restrict__ batch,
                                                  float* __restrict__ pooled) {
    int tid = threadIdx.x, lane = tid & 63, wid = tid >> 6;
    int hh = lane >> 5, c = lane & 31;          // half-wave id, half2 channel
    int node = blockIdx.x * 4 + wid;            // NN = 12500*4 exact
    const __half2* hv = (const __half2*)h16;
    int s = rowptr[node], e = rowptr[node + 1];
    float2 acc;
    if (hh == 0) {  // self-loop + bias only in half 0 (halves are summed later)
        float di = dinv[node], dd = di * di;
        float2 self = __half22float2(hv[node * 32 + c]);
        float2 bb = ((const float2*)b)[c];
        acc.x = dd * self.x + bb.x;
        acc.y = dd * self.y + bb.y;
    } else {
        acc.x = 0.f; acc.y = 0.f;
    }
    int nfull = (e - s) & ~7;
    int j = s + hh, jend = s + nfull;
    for (; j < jend; j += 8) {
        int2 p0 = ew[j], p1 = ew[j + 2], p2 = ew[j + 4], p3 = ew[j + 6];
        __half2 v0 = hv[p0.x * 32 + c];
        __half2 v1 = hv[p1.x * 32 + c];
        __half2 v2 = hv[p2.x * 32 + c];
        __half2 v3 = hv[p3.x * 32 + c];
        float w0 = __int_as_float(p0.y), w1 = __int_as_float(p1.y);
        float w2 = __int_as_float(p2.y), w3 = __int_as_float(p3.y);
        float2 f0 = __half22float2(v0), f1 = __half22float2(v1);
        float2 f2 = __half22float2(v2), f3 = __half22float2(v3);
        acc.x += w0 * f0.x + w1 * f1.x + w2 * f2.x + w3 * f3.x;
        acc.y += w0 * f0.y + w1 * f1.y + w2 * f2.y + w3 * f3.y;
    }
    for (; j < e; j += 2) {  // tail 0..7 edges, per-lane predicate
        int2 p = ew[j];
        __half2 v = hv[p.x * 32 + c];
        float w = __int_as_float(p.y);
        float2 f = __half22float2(v);
        acc.x += w * f.x;
        acc.y += w * f.y;
    }
    // combine the two half-wave partial sums (lane L ^ 32 holds same channels)
    acc.x += __shfl_xor(acc.x, 32, 64);
    acc.y += __shfl_xor(acc.y, 32, 64);
    if (hh == 0) {
        if (POOL) {
            int g = batch[node];
            atomicAdd(&pooled[g * HD + 2 * c], acc.x);
            atomicAdd(&pooled[g * HD + 2 * c + 1], acc.y);
        } else {
            ((__half2*)out16)[node * 32 + c] = __floats2half2_rn(acc.x, acc.y);
        }
    }
}

// out[g] = (pooled[g,:]/max(cnt,1)) . lin_W + lin_b   — one wave per graph
__global__ __launch_bounds__(64) void final_kernel(const float* __restrict__ pooled,
                                                   const float* __restrict__ cnt,
                                                   const float* __restrict__ lin_W,
                                                   const float* __restrict__ lin_b,
                                                   float* __restrict__ out) {
    int g = blockIdx.x, d = threadIdx.x;
    float v = pooled[g * HD + d] / fmaxf(cnt[g], 1.f) * lin_W[d];
#pragma unroll
    for (int off = 32; off > 0; off >>= 1) v += __shfl_down(v, off, 64);
    if (d == 0) out[g] = v + lin_b[0];
}

// ---------------------------------------------------------------------------
extern "C" void kernel_launch(void* const* d_in, const int* in_sizes, int n_in,
                              void* d_out, int out_size, void* d_ws, size_t ws_size,
                              hipStream_t stream) {
    const float* x     = (const float*)d_in[0];
    const float* W1    = (const float*)d_in[1];
    const float* b1    = (const float*)d_in[2];
    const float* W2    = (const float*)d_in[3];
    const float* b2    = (const float*)d_in[4];
    const float* W3    = (const float*)d_in[5];
    const float* b3    = (const float*)d_in[6];
    const float* lin_W = (const float*)d_in[7];
    const float* lin_b = (const float*)d_in[8];
    const int* edge_index = (const int*)d_in[9];   // [2, NE]: row then col
    const int* batch      = (const int*)d_in[10];
    const int* row = edge_index;
    const int* col = edge_index + NE;
    float* out = (float*)d_out;

    // workspace layout:
    // [h16 NN*HD half][A16 NN*HD half][ew NE int2][rank NE]
    // [cursor NN][pooled NG*HD][cnt NG][rowptr NN+2][dinv NN][bsum NB]
    __half* h16    = (__half*)d_ws;
    __half* A16    = h16 + (size_t)NN * HD;
    int2*   ew     = (int2*)(A16 + (size_t)NN * HD);
    int*    rank   = (int*)(ew + NE);
    int*    cursor = rank + NE;
    float*  pooled = (float*)(cursor + NN);
    float*  cnt    = pooled + NG * HD;
    int*    rowptr = (int*)(cnt + NG);
    float*  dinv   = (float*)(rowptr + NN + 2);
    int*    bsum   = (int*)(dinv + NN);

    // zero cursor|pooled|cnt (contiguous)
    const int ZN = NN + NG * HD + NG;
    zero_kernel<<<(ZN + 255) / 256, 256, 0, stream>>>(cursor, ZN);

    // Fused gemm1 + single atomic pass (rank/deg/cnt)
    gemm1_rank<<<GEMM_BLOCKS + EDGE_BLOCKS, 256, 0, stream>>>(
        x, W1, h16, col, batch, cursor, rank, cnt);

    // scan: cursor(=deg) -> rowptr, dinv
    block_reduce<<<NB, 256, 0, stream>>>(cursor, bsum);
    scan_bsum<<<1, 64, 0, stream>>>(bsum);
    block_scan<<<NB, 256, 0, stream>>>(cursor, bsum, rowptr, dinv);

    // atomic-free CSR fill
    fill_csr<<<EDGE_BLOCKS, 256, 0, stream>>>(row, col, rank, dinv, rowptr, ew);

    const int GB = NN / 4;  // gather blocks: 4 nodes (waves) each

    // Layer 1 aggregate: h16 -> A16
    gather_h16<false><<<GB, 256, 0, stream>>>(h16, rowptr, ew, dinv, b1, A16,
                                              batch, pooled);
    // Layer 2: relu(A16) -> h16 -> A16
    gemm64_f16<<<GEMM_BLOCKS, 256, 0, stream>>>(A16, W2, h16);
    gather_h16<false><<<GB, 256, 0, stream>>>(h16, rowptr, ew, dinv, b2, A16,
                                              batch, pooled);
    // Layer 3: relu(A16) -> h16 -> pooled (fused)
    gemm64_f16<<<GEMM_BLOCKS, 256, 0, stream>>>(A16, W3, h16);
    gather_h16<true><<<GB, 256, 0, stream>>>(h16, rowptr, ew, dinv, b3, nullptr,
                                             batch, pooled);

    final_kernel<<<NG, 64, 0, stream>>>(pooled, cnt, lin_W, lin_b, out);
}

// Round 6
// 283.336 us; speedup vs baseline: 2.7968x; 1.1575x over previous
//
#include <hip/hip_runtime.h>
#include <hip/hip_fp16.h>

// Problem constants (fixed by the reference file)
#define NN 50000     // nodes
#define NE 800000    // edges
#define HD 64        // feature dim (in and hidden)
#define NG 512       // graphs
#define NBK 196      // buckets: col >> 8, max 49999>>8 = 195
#define NBL 196      // edge blocks of 4096: ceil(NE/4096)
#define M_CNT (NBK * NBL)       // 38416 counts
#define NBS 151                 // scan blocks: ceil(M_CNT/256)
#define GEMM_BLOCKS 3125        // NN/16

// ---------------------------------------------------------------------------
__global__ void zero_kernel(int* __restrict__ p, int n) {
    int i = blockIdx.x * blockDim.x + threadIdx.x;
    if (i < n) p[i] = 0;
}

// ---------------------------------------------------------------------------
// Pass A: per-(block,bucket) edge counts via LDS histogram (no global atomics)
// + graph node counts via sorted-batch boundary detection (atomic-free).
__global__ __launch_bounds__(256) void bucket_count(const int* __restrict__ col,
                                                    const int* __restrict__ batch,
                                                    int* __restrict__ counts,
                                                    int* __restrict__ beg,
                                                    int* __restrict__ endx) {
    __shared__ int hist[256];
    int tid = threadIdx.x, blk = blockIdx.x;
    hist[tid] = 0;
    __syncthreads();
    int base = blk * 4096;
#pragma unroll
    for (int k = 0; k < 16; ++k) {
        int e = base + k * 256 + tid;
        if (e < NE) atomicAdd(&hist[col[e] >> 8], 1);
    }
    // batch boundaries (batch is sorted); grid covers 50176 >= NN threads
    int t = blk * 256 + tid;
    if (t < NN) {
        int g = batch[t];
        if (t == 0 || batch[t - 1] != g) beg[g] = t;
        if (t == NN - 1 || batch[t + 1] != g) endx[g] = t + 1;
    }
    __syncthreads();
    if (tid < NBK) counts[tid * NBL + blk] = hist[tid];  // bucket-major
}

// ---- 3-stage exclusive scan over counts[M_CNT] ----------------------------
__global__ __launch_bounds__(256) void block_reduce(const int* __restrict__ src,
                                                    int* __restrict__ bsum) {
    __shared__ int ws[4];
    int tid = threadIdx.x, lane = tid & 63, wid = tid >> 6;
    int i = blockIdx.x * 256 + tid;
    int v = (i < M_CNT) ? src[i] : 0;
#pragma unroll
    for (int off = 32; off > 0; off >>= 1) v += __shfl_down(v, off, 64);
    if (lane == 0) ws[wid] = v;
    __syncthreads();
    if (tid == 0) bsum[blockIdx.x] = ws[0] + ws[1] + ws[2] + ws[3];
}

__global__ __launch_bounds__(64) void scan_bsum(int* __restrict__ bsum) {
    int lane = threadIdx.x;
    int carry = 0;
    for (int base = 0; base < NBS; base += 64) {
        int i = base + lane;
        int v = (i < NBS) ? bsum[i] : 0;
        int inc = v;
#pragma unroll
        for (int off = 1; off < 64; off <<= 1) {
            int t = __shfl_up(inc, off, 64);
            if (lane >= off) inc += t;
        }
        if (i < NBS) bsum[i] = carry + inc - v;  // exclusive
        carry += __shfl(inc, 63, 64);
    }
}

__global__ __launch_bounds__(256) void block_scan(const int* __restrict__ src,
                                                  const int* __restrict__ bsum,
                                                  int* __restrict__ dst) {
    __shared__ int ws[4];
    int tid = threadIdx.x, lane = tid & 63, wid = tid >> 6;
    int i = blockIdx.x * 256 + tid;
    int v = (i < M_CNT) ? src[i] : 0;
    int inc = v;
#pragma unroll
    for (int off = 1; off < 64; off <<= 1) {
        int t = __shfl_up(inc, off, 64);
        if (lane >= off) inc += t;
    }
    if (lane == 63) ws[wid] = inc;
    __syncthreads();
    int woff = 0;
    for (int k = 0; k < wid; ++k) woff += ws[k];
    if (i < M_CNT) dst[i] = bsum[blockIdx.x] + woff + inc - v;
}

// ---------------------------------------------------------------------------
// Fused: blocks [0,GEMM_BLOCKS) do h16 = x @ W1 (fp32 in, fp16 out);
// blocks [GEMM_BLOCKS, +NBL) scatter edges into bucket-ordered packed[]
// using precomputed per-(bucket,block) offsets (LDS cursors only).
__global__ __launch_bounds__(256) void gemm1_scatter(const float* __restrict__ x,
                                                     const float* __restrict__ W1,
                                                     __half* __restrict__ h16,
                                                     const int* __restrict__ row,
                                                     const int* __restrict__ col,
                                                     const int* __restrict__ counts_ex,
                                                     unsigned* __restrict__ packed) {
    if (blockIdx.x < GEMM_BLOCKS) {
        __shared__ float Ws[64][64];   // 16 KB
        __shared__ float Is[16][64];   // 4 KB
        int t = threadIdx.x;
        for (int i = t; i < 64 * 64; i += 256) Ws[i >> 6][i & 63] = W1[i];
        int row0 = blockIdx.x * 16;
        for (int i = t; i < 16 * 64; i += 256)
            Is[i >> 6][i & 63] = x[(row0 + (i >> 6)) * HD + (i & 63)];
        __syncthreads();
        int c = t & 63, r4 = t >> 6;
        float a0 = 0.f, a1 = 0.f, a2 = 0.f, a3 = 0.f;
#pragma unroll
        for (int k = 0; k < 64; ++k) {
            float w = Ws[k][c];
            a0 += Is[r4 + 0][k] * w;
            a1 += Is[r4 + 4][k] * w;
            a2 += Is[r4 + 8][k] * w;
            a3 += Is[r4 + 12][k] * w;
        }
        h16[(row0 + r4 + 0) * HD + c] = __float2half(a0);
        h16[(row0 + r4 + 4) * HD + c] = __float2half(a1);
        h16[(row0 + r4 + 8) * HD + c] = __float2half(a2);
        h16[(row0 + r4 + 12) * HD + c] = __float2half(a3);
    } else {
        __shared__ int cur[256];
        int tid = threadIdx.x, blk = blockIdx.x - GEMM_BLOCKS;
        cur[tid] = 0;
        __syncthreads();
        int base = blk * 4096;
#pragma unroll
        for (int k = 0; k < 16; ++k) {
            int e = base + k * 256 + tid;
            if (e < NE) {
                int c = col[e], r = row[e];
                int b = c >> 8;
                int lpos = atomicAdd(&cur[b], 1);
                int pos = counts_ex[b * NBL + blk] + lpos;
                packed[pos] = (unsigned)r | ((unsigned)(c & 255) << 16);
            }
        }
    }
}

// ---------------------------------------------------------------------------
// D1: per-bucket LDS histogram + scan -> rowptr, dinv (no global atomics)
__global__ __launch_bounds__(256) void csr_rowptr(const unsigned* __restrict__ packed,
                                                  const int* __restrict__ counts_ex,
                                                  int* __restrict__ rowptr,
                                                  float* __restrict__ dinv) {
    __shared__ int hist[256];
    __shared__ int ws[4];
    int bkt = blockIdx.x, tid = threadIdx.x;
    int s = counts_ex[bkt * NBL];
    int e = (bkt == NBK - 1) ? NE : counts_ex[(bkt + 1) * NBL];
    hist[tid] = 0;
    __syncthreads();
    for (int j = s + tid; j < e; j += 256)
        atomicAdd(&hist[(packed[j] >> 16) & 255], 1);
    __syncthreads();
    int lane = tid & 63, wid = tid >> 6;
    int v = hist[tid], inc = v;
#pragma unroll
    for (int off = 1; off < 64; off <<= 1) {
        int t = __shfl_up(inc, off, 64);
        if (lane >= off) inc += t;
    }
    if (lane == 63) ws[wid] = inc;
    __syncthreads();
    int woff = 0;
    for (int k = 0; k < wid; ++k) woff += ws[k];
    int node = bkt * 256 + tid;
    if (node < NN) {
        rowptr[node] = s + woff + inc - v;      // exclusive
        dinv[node] = rsqrtf((float)(v + 1));    // +1 self-loop
    }
    if (bkt == 0 && tid == 0) rowptr[NN] = NE;
}

// D2: fill CSR (src, weight) via LDS cursors; rowptr/dinv reads are L2-hot
__global__ __launch_bounds__(256) void csr_fill(const unsigned* __restrict__ packed,
                                                const int* __restrict__ counts_ex,
                                                const int* __restrict__ rowptr,
                                                const float* __restrict__ dinv,
                                                int2* __restrict__ ew) {
    __shared__ int cur[256];
    int bkt = blockIdx.x, tid = threadIdx.x;
    int s = counts_ex[bkt * NBL];
    int e = (bkt == NBK - 1) ? NE : counts_ex[(bkt + 1) * NBL];
    cur[tid] = 0;
    __syncthreads();
    for (int j = s + tid; j < e; j += 256) {
        unsigned p = packed[j];
        int r = p & 0xFFFF;
        int lc = (p >> 16) & 255;
        int c = (bkt << 8) | lc;
        int slot = rowptr[c] + atomicAdd(&cur[lc], 1);
        float w = dinv[r] * dinv[c];
        ew[slot] = make_int2(r, __float_as_int(w));
    }
}

// ---------------------------------------------------------------------------
// h16 = relu(in16) @ W   (layers 2,3)
__global__ __launch_bounds__(256) void gemm64_f16(const __half* __restrict__ in,
                                                  const float* __restrict__ W,
                                                  __half* __restrict__ out) {
    __shared__ float Ws[64][64];
    __shared__ float Is[16][64];
    int t = threadIdx.x;
    for (int i = t; i < 64 * 64; i += 256) Ws[i >> 6][i & 63] = W[i];
    int row0 = blockIdx.x * 16;
    const __half2* in2 = (const __half2*)(in + (size_t)row0 * HD);
    for (int i = t; i < 16 * 32; i += 256) {
        float2 v = __half22float2(in2[i]);
        int r = i >> 5, c2 = (i & 31) * 2;
        Is[r][c2]     = fmaxf(v.x, 0.f);
        Is[r][c2 + 1] = fmaxf(v.y, 0.f);
    }
    __syncthreads();
    int c = t & 63, r4 = t >> 6;
    float a0 = 0.f, a1 = 0.f, a2 = 0.f, a3 = 0.f;
#pragma unroll
    for (int k = 0; k < 64; ++k) {
        float w = Ws[k][c];
        a0 += Is[r4 + 0][k] * w;
        a1 += Is[r4 + 4][k] * w;
        a2 += Is[r4 + 8][k] * w;
        a3 += Is[r4 + 12][k] * w;
    }
    out[(row0 + r4 + 0) * HD + c] = __float2half(a0);
    out[(row0 + r4 + 4) * HD + c] = __float2half(a1);
    out[(row0 + r4 + 8) * HD + c] = __float2half(a2);
    out[(row0 + r4 + 12) * HD + c] = __float2half(a3);
}

// ---------------------------------------------------------------------------
// CSR gather, fp16 features: ONE node per wave; two half-waves split the edge
// stream; 32 lanes x half2 = full 128B row per edge. fp32 accumulate.
template <bool POOL>
__global__ __launch_bounds__(256) void gather_h16(const __half* __restrict__ h16,
                                                  const int* __restrict__ rowptr,
                                                  const int2* __restrict__ ew,
                                                  const float* __restrict__ dinv,
                                                  const float* __restrict__ b,
                                                  __half* __restrict__ out16,
                                                  const int* __restrict__ batch,
                                                  float* __restrict__ pooled) {
    int tid = threadIdx.x, lane = tid & 63, wid = tid >> 6;
    int hh = lane >> 5, c = lane & 31;          // half-wave id, half2 channel
    int node = blockIdx.x * 4 + wid;            // NN = 12500*4 exact
    const __half2* hv = (const __half2*)h16;
    int s = rowptr[node], e = rowptr[node + 1];
    float2 acc;
    if (hh == 0) {  // self-loop + bias only in half 0 (halves summed later)
        float di = dinv[node], dd = di * di;
        float2 self = __half22float2(hv[node * 32 + c]);
        float2 bb = ((const float2*)b)[c];
        acc.x = dd * self.x + bb.x;
        acc.y = dd * self.y + bb.y;
    } else {
        acc.x = 0.f; acc.y = 0.f;
    }
    int nfull = (e - s) & ~7;
    int j = s + hh, jend = s + nfull;
    for (; j < jend; j += 8) {
        int2 p0 = ew[j], p1 = ew[j + 2], p2 = ew[j + 4], p3 = ew[j + 6];
        __half2 v0 = hv[p0.x * 32 + c];
        __half2 v1 = hv[p1.x * 32 + c];
        __half2 v2 = hv[p2.x * 32 + c];
        __half2 v3 = hv[p3.x * 32 + c];
        float w0 = __int_as_float(p0.y), w1 = __int_as_float(p1.y);
        float w2 = __int_as_float(p2.y), w3 = __int_as_float(p3.y);
        float2 f0 = __half22float2(v0), f1 = __half22float2(v1);
        float2 f2 = __half22float2(v2), f3 = __half22float2(v3);
        acc.x += w0 * f0.x + w1 * f1.x + w2 * f2.x + w3 * f3.x;
        acc.y += w0 * f0.y + w1 * f1.y + w2 * f2.y + w3 * f3.y;
    }
    for (; j < e; j += 2) {
        int2 p = ew[j];
        __half2 v = hv[p.x * 32 + c];
        float w = __int_as_float(p.y);
        float2 f = __half22float2(v);
        acc.x += w * f.x;
        acc.y += w * f.y;
    }
    acc.x += __shfl_xor(acc.x, 32, 64);
    acc.y += __shfl_xor(acc.y, 32, 64);
    if (hh == 0) {
        if (POOL) {
            int g = batch[node];
            atomicAdd(&pooled[g * HD + 2 * c], acc.x);
            atomicAdd(&pooled[g * HD + 2 * c + 1], acc.y);
        } else {
            ((__half2*)out16)[node * 32 + c] = __floats2half2_rn(acc.x, acc.y);
        }
    }
}

// out[g] = (pooled[g,:]/max(cnt,1)) . lin_W + lin_b   — one wave per graph
__global__ __launch_bounds__(64) void final_kernel(const float* __restrict__ pooled,
                                                   const int* __restrict__ beg,
                                                   const int* __restrict__ endx,
                                                   const float* __restrict__ lin_W,
                                                   const float* __restrict__ lin_b,
                                                   float* __restrict__ out) {
    int g = blockIdx.x, d = threadIdx.x;
    float cnt = (float)(endx[g] - beg[g]);
    float v = pooled[g * HD + d] / fmaxf(cnt, 1.f) * lin_W[d];
#pragma unroll
    for (int off = 32; off > 0; off >>= 1) v += __shfl_down(v, off, 64);
    if (d == 0) out[g] = v + lin_b[0];
}

// ---------------------------------------------------------------------------
extern "C" void kernel_launch(void* const* d_in, const int* in_sizes, int n_in,
                              void* d_out, int out_size, void* d_ws, size_t ws_size,
                              hipStream_t stream) {
    const float* x     = (const float*)d_in[0];
    const float* W1    = (const float*)d_in[1];
    const float* b1    = (const float*)d_in[2];
    const float* W2    = (const float*)d_in[3];
    const float* b2    = (const float*)d_in[4];
    const float* W3    = (const float*)d_in[5];
    const float* b3    = (const float*)d_in[6];
    const float* lin_W = (const float*)d_in[7];
    const float* lin_b = (const float*)d_in[8];
    const int* edge_index = (const int*)d_in[9];   // [2, NE]: row then col
    const int* batch      = (const int*)d_in[10];
    const int* row = edge_index;
    const int* col = edge_index + NE;
    float* out = (float*)d_out;

    // workspace layout (4B units):
    // [h16 NN*HD half][A16 NN*HD half][ew NE int2][packed NE uint]
    // [counts M][counts_ex M][rowptr NN+2][dinv NN][bsum 256]
    // [pooled NG*HD][beg NG][endx NG]
    __half*   h16       = (__half*)d_ws;
    __half*   A16       = h16 + (size_t)NN * HD;
    int2*     ew        = (int2*)(A16 + (size_t)NN * HD);
    unsigned* packed    = (unsigned*)(ew + NE);
    int*      counts    = (int*)(packed + NE);
    int*      counts_ex = counts + M_CNT;
    int*      rowptr    = counts_ex + M_CNT;
    float*    dinv      = (float*)(rowptr + NN + 2);
    int*      bsum      = (int*)(dinv + NN);
    float*    pooled    = (float*)(bsum + 256);
    int*      beg       = (int*)(pooled + NG * HD);
    int*      endx      = beg + NG;

    // zero pooled|beg|endx (contiguous)
    const int ZN = NG * HD + 2 * NG;
    zero_kernel<<<(ZN + 255) / 256, 256, 0, stream>>>((int*)pooled, ZN);

    // CSR build: count -> scan -> (scatter fused w/ gemm1) -> rowptr -> fill
    bucket_count<<<NBL, 256, 0, stream>>>(col, batch, counts, beg, endx);
    block_reduce<<<NBS, 256, 0, stream>>>(counts, bsum);
    scan_bsum<<<1, 64, 0, stream>>>(bsum);
    block_scan<<<NBS, 256, 0, stream>>>(counts, bsum, counts_ex);
    gemm1_scatter<<<GEMM_BLOCKS + NBL, 256, 0, stream>>>(x, W1, h16, row, col,
                                                         counts_ex, packed);
    csr_rowptr<<<NBK, 256, 0, stream>>>(packed, counts_ex, rowptr, dinv);
    csr_fill<<<NBK, 256, 0, stream>>>(packed, counts_ex, rowptr, dinv, ew);

    const int GB = NN / 4;  // gather blocks: 4 nodes (waves) each

    // Layer 1 aggregate: h16 -> A16
    gather_h16<false><<<GB, 256, 0, stream>>>(h16, rowptr, ew, dinv, b1, A16,
                                              batch, pooled);
    // Layer 2: relu(A16) -> h16 -> A16
    gemm64_f16<<<GEMM_BLOCKS, 256, 0, stream>>>(A16, W2, h16);
    gather_h16<false><<<GB, 256, 0, stream>>>(h16, rowptr, ew, dinv, b2, A16,
                                              batch, pooled);
    // Layer 3: relu(A16) -> h16 -> pooled (fused)
    gemm64_f16<<<GEMM_BLOCKS, 256, 0, stream>>>(A16, W3, h16);
    gather_h16<true><<<GB, 256, 0, stream>>>(h16, rowptr, ew, dinv, b3, nullptr,
                                             batch, pooled);

    final_kernel<<<NG, 64, 0, stream>>>(pooled, beg, endx, lin_W, lin_b, out);
}